// Round 4
// baseline (612.048 us; speedup 1.0000x reference)
//
#include <hip/hip_runtime.h>

// GraphVAE fused persistent kernel, round 4.
// R3 post-mortem: ~9us/iter was the producer-side vmcnt drain on SCATTERED
// 4B write-through X stores (64 lanes -> 64 lines, 20 blocks x 80 contended
// lines at the coherence point), not cache-wide coherence ops (R1==R3 proved
// that). This round:
//  1. X exchanged in X^T layout: LDS transpose -> 5-line coalesced f2 stores
//     per block; consumer transposes back during LDS staging writes.
//  2. B rows computed per-block into LDS (2x redundant one-time dots) -> no
//     global Bm, no scatter, one fewer sync phase.
//  3. E2 stages hT through LDS in 4 chunks (coalesced) instead of 512 serial
//     per-thread sc1 loads.
// Sync stays: relaxed sc1 slot==flag (payload = norm partial), poll->barrier.

#define NN 80
#define PBLK 20            // blocks; each owns 4 columns of X
#define TPB 320            // 5 waves
#define RP 84              // Xs row pad (84*4B rows, 16B-aligned, b128-friendly)
#define RPB 84             // BmL row pad
#define NCOLS 13           // owned feature columns per block (ceil(256/20))

// ---- relaxed agent-scope (sc1) accessors: coherent, no cache-wide ops ----
__device__ __forceinline__ float ld_f32g(const float* p){
  return __hip_atomic_load((float*)p, __ATOMIC_RELAXED, __HIP_MEMORY_SCOPE_AGENT);
}
__device__ __forceinline__ void st_f32g(float* p, float v){
  __hip_atomic_store(p, v, __ATOMIC_RELAXED, __HIP_MEMORY_SCOPE_AGENT);
}
__device__ __forceinline__ int ld_i32g(const int* p){
  return __hip_atomic_load((int*)p, __ATOMIC_RELAXED, __HIP_MEMORY_SCOPE_AGENT);
}
__device__ __forceinline__ void st_i32g(int* p, int v){
  __hip_atomic_store(p, v, __ATOMIC_RELAXED, __HIP_MEMORY_SCOPE_AGENT);
}
__device__ __forceinline__ float2 ld_f2g(const float* p){
  union { unsigned long long u; float2 f; } c;
  c.u = __hip_atomic_load((unsigned long long*)p, __ATOMIC_RELAXED, __HIP_MEMORY_SCOPE_AGENT);
  return c.f;
}
__device__ __forceinline__ void st_f2g(float* p, float a, float b){
  union { unsigned long long u; float2 f; } c; c.f.x = a; c.f.y = b;
  __hip_atomic_store((unsigned long long*)p, c.u, __ATOMIC_RELAXED, __HIP_MEMORY_SCOPE_AGENT);
}

__device__ __forceinline__ float wave_sum(float v){
  #pragma unroll
  for (int k = 32; k >= 1; k >>= 1) v += __shfl_xor(v, k, 64);
  return v;
}

// GCN aggregate(+self loop)+bias+BatchNorm(train,biased,two-pass var)+ReLU
// for owned columns; result left in accL. inL/accL: LDS [NCOLS][80].
__device__ void gcn_bn_relu(const float* inL, const float* bias, const float* gamma,
                            const float* beta, const int* ei, const float* dinvS,
                            float* accL, float* colstat, int p, int tid)
{
  for (int u = tid; u < NCOLS*NN; u += TPB) accL[u] = 0.f;
  __syncthreads();
  for (int cl = 0; cl < NCOLS; cl++){
    int c = p + PBLK*cl; if (c >= 256) break;
    const float* col = &inL[cl*NN];
    for (int e = tid; e < 800; e += TPB){
      int s = ei[e], d = ei[800+e];
      atomicAdd(&accL[cl*NN + d], col[s]*dinvS[s]*dinvS[d]);
    }
  }
  __syncthreads();
  for (int u = tid; u < NCOLS*NN; u += TPB){
    int cl = u/NN, i = u - cl*NN, c = p + PBLK*cl;
    if (c < 256) accL[u] += inL[u]*dinvS[i]*dinvS[i] + bias[c];
  }
  __syncthreads();
  if (tid < 16*NCOLS){
    int g = tid >> 4, s = tid & 15, c = p + PBLK*g;
    if (c < 256){
      float r[5];
      float sm = 0.f;
      #pragma unroll
      for (int i = 0; i < 5; i++){ r[i] = accL[g*NN + s + 16*i]; sm += r[i]; }
      #pragma unroll
      for (int k = 1; k < 16; k <<= 1) sm += __shfl_xor(sm, k, 64);
      float m = sm*(1.0f/NN);
      float sq = 0.f;
      #pragma unroll
      for (int i = 0; i < 5; i++){ float d = r[i]-m; sq += d*d; }
      #pragma unroll
      for (int k = 1; k < 16; k <<= 1) sq += __shfl_xor(sq, k, 64);
      if (s == 0){
        colstat[2*g]   = m;
        colstat[2*g+1] = 1.0f/sqrtf(sq*(1.0f/NN) + 1e-5f);
      }
    }
  }
  __syncthreads();
  for (int u = tid; u < NCOLS*NN; u += TPB){
    int cl = u/NN, c = p + PBLK*cl;
    if (c < 256){
      float hv = gamma[c]*(accL[u]-colstat[2*cl])*colstat[2*cl+1] + beta[c];
      accL[u] = fmaxf(hv, 0.f);
    }
  }
  __syncthreads();
}

__global__ __launch_bounds__(TPB, 1) void gvae_fused(
    const float* __restrict__ x,  const int* __restrict__ ei, const int* __restrict__ adj,
    const float* __restrict__ eps,
    const float* __restrict__ W1, const float* __restrict__ b1, const float* __restrict__ g1, const float* __restrict__ bt1,
    const float* __restrict__ W2, const float* __restrict__ b2, const float* __restrict__ g2, const float* __restrict__ bt2,
    const float* __restrict__ Wmu,const float* __restrict__ bmu,const float* __restrict__ Wlv,const float* __restrict__ blv,
    const float* __restrict__ We1,const float* __restrict__ be1,const float* __restrict__ We2,const float* __restrict__ be2,
    float* __restrict__ out, float* __restrict__ ws)
{
  const int tid = threadIdx.x;
  const int p   = blockIdx.x;

  // ---- workspace (host memsets flags+slots to 0) ----
  int*   flag  = (int*)ws;            // [32]  phase stamps
  float* slots = ws + 32;             // [50*20] per-iter partial ||R||^2 (>0)
  float* gvS   = ws + 1056;           // [256] pooled g_vec exchange
  float* hT    = ws + 1312;           // [256*80] layer-1 output, transposed
  float* Xb0   = hT + 20480;          // MPM ping, X^T layout: flat[a*80+j]
  float* Xb1   = Xb0 + 6400;          // MPM pong

  // poolS: Xs [80][RP] in MPM; hT chunk [64][80] (20KB) in E2.
  __shared__ float poolS[NN*RP];
  __shared__ float MtL[4*RP];
  __shared__ float xnT[4*NN];         // X^T staging for coalesced export
  __shared__ float BmL[4*RPB];        // B rows 4p..4p+3 (local only)
  __shared__ float red[8];
  __shared__ float scS;
  __shared__ float dinvS[NN];
  __shared__ float accL[NCOLS*NN];
  __shared__ float hL[NCOLS*NN];
  __shared__ float gv[256], zv[128], t1v[256];
  __shared__ float colstat[2*NCOLS];
  float* Xs = poolS;

  // ---------------- E0: degrees (block-redundant) ---------------------------
  for (int i = tid; i < NN; i += TPB) accL[i] = 1.0f;            // self loop
  __syncthreads();
  for (int e = tid; e < 800; e += TPB) atomicAdd(&accL[ei[800+e]], 1.0f);
  __syncthreads();
  for (int i = tid; i < NN; i += TPB) dinvS[i] = 1.0f/sqrtf(accL[i]);
  __syncthreads();

  // ---------------- E1: GEMM1 x@W1 (own cols) + GCN1 -> hT ------------------
  for (int u = tid; u < NCOLS*NN; u += TPB){
    int cl = u/NN, i = u - cl*NN, c = p + PBLK*cl;
    if (c < 256){
      float s = 0.f;
      for (int k = 0; k < 64; k++) s += x[i*64+k]*W1[k*256+c];
      hL[u] = s;
    }
  }
  __syncthreads();
  gcn_bn_relu(hL, b1, g1, bt1, ei, dinvS, accL, colstat, p, tid);
  for (int u2 = tid; u2 < 40*NCOLS; u2 += TPB){       // export own rows of hT
    int cl = u2/40, i2 = (u2 - cl*40)*2, c = p + PBLK*cl;
    if (c < 256) st_f2g(&hT[c*NN+i2], accL[cl*NN+i2], accL[cl*NN+i2+1]);
  }
  __syncthreads();                                     // drains export stores
  if (tid == 0) st_i32g(&flag[p], 1);

  // ---------------- E2: GEMM2 h@W2 via 4 chunked LDS tiles ------------------
  if (tid < PBLK) while (ld_i32g(&flag[tid]) < 1) {}
  __syncthreads();                                     // gate ALL waves
  {
    const int cl = tid/20, iq = tid - 20*cl, c = p + PBLK*cl;
    const int i0 = 4*iq;
    const bool valid = (tid < 20*NCOLS) && (c < 256);
    float a0=0.f, a1=0.f, a2=0.f, a3=0.f;
    for (int ch = 0; ch < 4; ch++){
      const int k0 = 64*ch;
      __syncthreads();                                 // chunk buffer free
      #pragma unroll
      for (int r = 0; r < 8; r++){                     // 5120 floats coalesced
        int u = tid + TPB*r;
        float2 hv = ld_f2g(&hT[k0*NN + 2*u]);
        poolS[2*u] = hv.x; poolS[2*u+1] = hv.y;
      }
      __syncthreads();
      if (valid){
        for (int kk = 0; kk < 64; kk++){
          float wv = W2[(k0+kk)*256 + c];
          float4 hv = *(const float4*)&poolS[kk*NN + i0];
          a0 += hv.x*wv; a1 += hv.y*wv; a2 += hv.z*wv; a3 += hv.w*wv;
        }
      }
    }
    __syncthreads();
    if (valid){
      hL[cl*NN+i0+0]=a0; hL[cl*NN+i0+1]=a1; hL[cl*NN+i0+2]=a2; hL[cl*NN+i0+3]=a3;
    }
  }
  __syncthreads();
  gcn_bn_relu(hL, b2, g2, bt2, ei, dinvS, accL, colstat, p, tid);
  if (tid < 16*NCOLS){                                 // pool own cols -> gvS
    int g = tid >> 4, s = tid & 15, c = p + PBLK*g;
    if (c < 256){
      float sm = 0.f;
      #pragma unroll
      for (int i = 0; i < 5; i++) sm += accL[g*NN + s + 16*i];
      #pragma unroll
      for (int k = 1; k < 16; k <<= 1) sm += __shfl_xor(sm, k, 64);
      if (s == 0) st_f32g(&gvS[c], sm*(1.0f/NN));
    }
  }
  __syncthreads();                                     // drains gvS stores
  if (tid == 0) st_i32g(&flag[p], 2);

  // ---------------- E3: z, t1 (block-redundant; weights are inputs) ---------
  if (tid < PBLK) while (ld_i32g(&flag[tid]) < 2) {}
  __syncthreads();
  if (tid < 256) gv[tid] = ld_f32g(&gvS[tid]);
  __syncthreads();
  if (tid < 128){
    int c = tid;
    float smu = bmu[c], slv = blv[c];
    for (int k = 0; k < 256; k++){
      float g = gv[k];
      smu += g*Wmu[k*128+c];
      slv += g*Wlv[k*128+c];
    }
    slv = fminf(fmaxf(slv, -4.f), 4.f);
    zv[c] = smu + eps[c]*expf(0.5f*slv);
  }
  __syncthreads();
  if (tid < 256){
    float s = be1[tid];
    for (int k = 0; k < 128; k++) s += zv[k]*We1[k*256+tid];
    t1v[tid] = fmaxf(s, 0.f);
  }
  __syncthreads();

  // ---------------- E4: OWN B rows 4p..4p+3 -> BmL (LDS only) ---------------
  // 2x redundant dots vs triangle split, but zero global traffic and no sync.
  if (tid < 316){
    int r = tid/79, jj = tid - 79*r;
    int a = 4*p + r;
    int j = jj + (jj >= a ? 1 : 0);
    int lo = a < j ? a : j, hi = a < j ? j : a;
    int off = lo*(159-lo)/2 + (hi-lo-1);               // triu(k=1) flat index
    float s = be2[off];
    for (int k = 0; k < 256; k++) s += t1v[k]*We2[k*3160+off];
    BmL[r*RPB + j] = 1.0f/(1.0f + expf(-s));
  } else {
    int r = tid-316;
    BmL[r*RPB + 4*p + r] = 1.0f;                       // diag = 1
  }
  __syncthreads();

  // ---------------- E5: per-lane register caches ----------------------------
  const int w  = tid >> 6;
  const int l  = tid & 63;
  const int il = 16*w + (l & 15);    // row i (== j in M phase)
  const int ae = l >> 4;             // local column 0..3
  const int al = 4*p + ae;           // global column a

  float4 Af[20];
  float degA = 0.f;
  #pragma unroll
  for (int c = 0; c < 20; c++){
    int j0 = 4*c;
    int4 ar = *(const int4*)&adj[il*NN+j0];
    int q0 = adj[(j0+0)*NN+il];
    int q1 = adj[(j0+1)*NN+il];
    int q2 = adj[(j0+2)*NN+il];
    int q3 = adj[(j0+3)*NN+il];
    float4 a;
    a.x = ((ar.x|q0) != 0 || il == j0+0) ? 1.f : 0.f;
    a.y = ((ar.y|q1) != 0 || il == j0+1) ? 1.f : 0.f;
    a.z = ((ar.z|q2) != 0 || il == j0+2) ? 1.f : 0.f;
    a.w = ((ar.w|q3) != 0 || il == j0+3) ? 1.f : 0.f;
    Af[c] = a;
    degA += (a.x+a.y)+(a.z+a.w);
  }

  float4 Bf[20];
  float degB = 0.f;
  #pragma unroll
  for (int c = 0; c < 20; c++){
    float4 b = *(const float4*)&BmL[ae*RPB + 4*c];
    Bf[c] = b;
    degB += (b.x+b.y)+(b.z+b.w);
  }
  const float ns = 1.0f/(fabsf(degA-degB)+1.0f);
  {                                   // b==a exclusion (valid since X,B >= 0)
    if      (ae == 0) Bf[p].x = 0.f;
    else if (ae == 1) Bf[p].y = 0.f;
    else if (ae == 2) Bf[p].z = 0.f;
    else              Bf[p].w = 0.f;
  }
  __syncthreads();                    // BmL reads done; poolS reuse below

  // ---------------- MPM: 50 iterations, slot==flag sync ---------------------
  for (int u = tid; u < NN*RP; u += TPB) Xs[u] = 1.0f/NN;
  __syncthreads();
  float xn = 0.f;
  for (int t = 0; t < 50; t++){
    float sc = 1.0f;
    if (t > 0){
      float pv = 0.f;
      if (tid < PBLK){                // wave0 polls the 20 producer slots
        const float* sp = &slots[(t-1)*PBLK + tid];
        do { pv = ld_f32g(sp); } while (pv == 0.0f);
      }
      if (w == 0){
        float v = pv;
        #pragma unroll
        for (int k = 1; k < 32; k <<= 1) v += __shfl_xor(v, k, 64);
        if (tid == 0) scS = 1.0f/sqrtf(v);
      }
      __syncthreads();                // gate ALL waves behind poll
      sc = scS;
      // stage X^T (coalesced f2 reads) -> row-major Xs (transposed LDS write)
      const float* Xsrc = ((t-1)&1) ? Xb1 : Xb0;
      #pragma unroll
      for (int q = 0; q < 10; q++){
        int u = tid + TPB*q;
        int a = u/40, j2 = (u - 40*a)*2;
        float2 xv = ld_f2g(&Xsrc[a*NN + j2]);
        Xs[j2*RP + a]     = xv.x;     // ~10-way bank conflict, accepted
        Xs[(j2+1)*RP + a] = xv.y;
      }
      __syncthreads();
    }

    // M[il][al] = max_{b != al} X[il][b]*B[al][b]
    float m = 0.f;
    #pragma unroll
    for (int c = 0; c < 20; c++){
      float4 xv = *(const float4*)&Xs[il*RP+4*c];
      float p0 = xv.x*Bf[c].x, p1 = xv.y*Bf[c].y, p2 = xv.z*Bf[c].z, p3 = xv.w*Bf[c].w;
      m = fmaxf(m, fmaxf(fmaxf(p0,p1), fmaxf(p2,p3)));
    }
    float xnode = Xs[il*RP+al];
    MtL[ae*RP+il] = m;
    __syncthreads();

    // edge[il][al] = sum_j A[il][j]*M[j][al] - M[il][al]   (A[i][i]=1)
    float e0=0.f,e1=0.f,e2=0.f,e3=0.f;
    #pragma unroll
    for (int c = 0; c < 20; c++){
      float4 mv = *(const float4*)&MtL[ae*RP+4*c];
      e0 += Af[c].x*mv.x; e1 += Af[c].y*mv.y; e2 += Af[c].z*mv.z; e3 += Af[c].w*mv.w;
    }
    float edge = ((e0+e1)+(e2+e3)) - m;
    xn = sc*(ns*xnode + edge);        // R_{t+1} = f(R_t/||R_t||), norm deferred

    if (t < 49) xnT[ae*NN + il] = xn; // LDS transpose for coalesced export
    float v2 = wave_sum(xn*xn);
    if (l == 0) red[w] = v2;
    __syncthreads();
    if (t < 49 && tid < 160){         // own X^T slab: 5 lines, coalesced
      float* Xdst = (t&1) ? Xb1 : Xb0;
      st_f2g(&Xdst[p*320 + 2*tid], xnT[2*tid], xnT[2*tid+1]);
    }
    __syncthreads();                  // per-wave vmcnt drained before barrier
    if (tid == 0){
      float tot = ((red[0]+red[1])+(red[2]+red[3]))+red[4];
      st_f32g(&slots[t*PBLK+p], tot); // slot is both payload and flag
    }
  }

  // final normalization of iteration 49 (xn is in registers)
  {
    float pv = 0.f;
    if (tid < PBLK){
      const float* sp = &slots[49*PBLK + tid];
      do { pv = ld_f32g(sp); } while (pv == 0.0f);
    }
    if (w == 0){
      float v = pv;
      #pragma unroll
      for (int k = 1; k < 32; k <<= 1) v += __shfl_xor(v, k, 64);
      if (tid == 0) scS = 1.0f/sqrtf(v);
    }
    __syncthreads();
    out[il*NN+al] = xn * scS;
  }
}

extern "C" void kernel_launch(void* const* d_in, const int* in_sizes, int n_in,
                              void* d_out, int out_size, void* d_ws, size_t ws_size,
                              hipStream_t stream)
{
  (void)in_sizes; (void)n_in; (void)out_size; (void)ws_size;
  // zero flags (128B) + slots (50*20*4B) — ws is re-poisoned to 0xAA each launch
  hipMemsetAsync(d_ws, 0, 4224, stream);
  gvae_fused<<<PBLK, TPB, 0, stream>>>(
      (const float*)d_in[0],  (const int*)d_in[1],   (const int*)d_in[2],   (const float*)d_in[3],
      (const float*)d_in[4],  (const float*)d_in[5],  (const float*)d_in[6],  (const float*)d_in[7],
      (const float*)d_in[8],  (const float*)d_in[9],  (const float*)d_in[10], (const float*)d_in[11],
      (const float*)d_in[12], (const float*)d_in[13], (const float*)d_in[14], (const float*)d_in[15],
      (const float*)d_in[16], (const float*)d_in[17], (const float*)d_in[18], (const float*)d_in[19],
      (float*)d_out, (float*)d_ws);
}

// Round 5
// 575.116 us; speedup vs baseline: 1.0642x; 1.0642x over previous
//
#include <hip/hip_runtime.h>

// GraphVAE fused persistent kernel, round 5.
// R1/R3/R4 post-mortem: three different flag/slot sync schemes all cost
// ~8-10us/iteration -> the floor is the serial visibility chain
// (store -> drain -> flag -> poll(contended) -> load), not coherence ops.
// This round: DATA-AS-FLAG. All MPM values are strictly positive
// (ns>=1/81, X0>0, B>0 => xn>0), so with one fresh ZEROED buffer per
// iteration (50 x 25.6KB), "element != 0" == "element ready". No flags, no
// producer drain-before-flag, no slot contention, no sumsq exchange (norm
// recomputed locally from the staged slab). 2 block barriers/iter (was 4).

#define NN 80
#define PBLK 20            // blocks; each owns 4 columns of X
#define TPB 320            // 5 waves
#define RP 84              // Xs row pad (16B-aligned rows, conflict-free)
#define RPB 84             // BmL row pad
#define NCOLS 13           // owned feature columns per block (ceil(256/20))

// ---- relaxed agent-scope (sc1) accessors: coherent, no cache-wide ops ----
__device__ __forceinline__ float ld_f32g(const float* p){
  return __hip_atomic_load((float*)p, __ATOMIC_RELAXED, __HIP_MEMORY_SCOPE_AGENT);
}
__device__ __forceinline__ void st_f32g(float* p, float v){
  __hip_atomic_store(p, v, __ATOMIC_RELAXED, __HIP_MEMORY_SCOPE_AGENT);
}
__device__ __forceinline__ int ld_i32g(const int* p){
  return __hip_atomic_load((int*)p, __ATOMIC_RELAXED, __HIP_MEMORY_SCOPE_AGENT);
}
__device__ __forceinline__ void st_i32g(int* p, int v){
  __hip_atomic_store(p, v, __ATOMIC_RELAXED, __HIP_MEMORY_SCOPE_AGENT);
}
__device__ __forceinline__ float2 ld_f2g(const float* p){
  union { unsigned long long u; float2 f; } c;
  c.u = __hip_atomic_load((unsigned long long*)p, __ATOMIC_RELAXED, __HIP_MEMORY_SCOPE_AGENT);
  return c.f;
}
__device__ __forceinline__ void st_f2g(float* p, float a, float b){
  union { unsigned long long u; float2 f; } c; c.f.x = a; c.f.y = b;
  __hip_atomic_store((unsigned long long*)p, c.u, __ATOMIC_RELAXED, __HIP_MEMORY_SCOPE_AGENT);
}

__device__ __forceinline__ float wave_sum(float v){
  #pragma unroll
  for (int k = 32; k >= 1; k >>= 1) v += __shfl_xor(v, k, 64);
  return v;
}

// GCN aggregate(+self loop)+bias+BatchNorm(train,biased,two-pass var)+ReLU
// for owned columns; result left in accL. inL/accL: LDS [NCOLS][80].
__device__ void gcn_bn_relu(const float* inL, const float* bias, const float* gamma,
                            const float* beta, const int* ei, const float* dinvS,
                            float* accL, float* colstat, int p, int tid)
{
  for (int u = tid; u < NCOLS*NN; u += TPB) accL[u] = 0.f;
  __syncthreads();
  for (int cl = 0; cl < NCOLS; cl++){
    int c = p + PBLK*cl; if (c >= 256) break;
    const float* col = &inL[cl*NN];
    for (int e = tid; e < 800; e += TPB){
      int s = ei[e], d = ei[800+e];
      atomicAdd(&accL[cl*NN + d], col[s]*dinvS[s]*dinvS[d]);
    }
  }
  __syncthreads();
  for (int u = tid; u < NCOLS*NN; u += TPB){
    int cl = u/NN, i = u - cl*NN, c = p + PBLK*cl;
    if (c < 256) accL[u] += inL[u]*dinvS[i]*dinvS[i] + bias[c];
  }
  __syncthreads();
  if (tid < 16*NCOLS){
    int g = tid >> 4, s = tid & 15, c = p + PBLK*g;
    if (c < 256){
      float r[5];
      float sm = 0.f;
      #pragma unroll
      for (int i = 0; i < 5; i++){ r[i] = accL[g*NN + s + 16*i]; sm += r[i]; }
      #pragma unroll
      for (int k = 1; k < 16; k <<= 1) sm += __shfl_xor(sm, k, 64);
      float m = sm*(1.0f/NN);
      float sq = 0.f;
      #pragma unroll
      for (int i = 0; i < 5; i++){ float d = r[i]-m; sq += d*d; }
      #pragma unroll
      for (int k = 1; k < 16; k <<= 1) sq += __shfl_xor(sq, k, 64);
      if (s == 0){
        colstat[2*g]   = m;
        colstat[2*g+1] = 1.0f/sqrtf(sq*(1.0f/NN) + 1e-5f);
      }
    }
  }
  __syncthreads();
  for (int u = tid; u < NCOLS*NN; u += TPB){
    int cl = u/NN, c = p + PBLK*cl;
    if (c < 256){
      float hv = gamma[c]*(accL[u]-colstat[2*cl])*colstat[2*cl+1] + beta[c];
      accL[u] = fmaxf(hv, 0.f);
    }
  }
  __syncthreads();
}

__global__ __launch_bounds__(TPB, 1) void gvae_fused(
    const float* __restrict__ x,  const int* __restrict__ ei, const int* __restrict__ adj,
    const float* __restrict__ eps,
    const float* __restrict__ W1, const float* __restrict__ b1, const float* __restrict__ g1, const float* __restrict__ bt1,
    const float* __restrict__ W2, const float* __restrict__ b2, const float* __restrict__ g2, const float* __restrict__ bt2,
    const float* __restrict__ Wmu,const float* __restrict__ bmu,const float* __restrict__ Wlv,const float* __restrict__ blv,
    const float* __restrict__ We1,const float* __restrict__ be1,const float* __restrict__ We2,const float* __restrict__ be2,
    float* __restrict__ out, float* __restrict__ ws)
{
  const int tid = threadIdx.x;
  const int p   = blockIdx.x;

  // ---- workspace: [Xbase 50*6400 | eflag 20*32 ints | gvS 256 | hT 20480]
  // host memsets Xbase+eflag (1,282,560 B) to zero each launch.
  float* Xbase = ws;                   // 50 per-iteration U buffers (data-as-flag)
  int*   eflag = (int*)ws + 320000;    // encoder flags, padded 128B apart
  float* gvS   = ws + 320640;          // pooled g_vec exchange
  float* hT    = ws + 320896;          // layer-1 output, transposed [256][80]

  // poolS: Xs [80][RP] in MPM; hT chunk [64][80] in E2.
  __shared__ float poolS[NN*RP];
  __shared__ float MtL[4*RP];
  __shared__ float BmL[4*RPB];         // B rows 4p..4p+3 (local only)
  __shared__ float red[8];
  __shared__ float dinvS[NN];
  __shared__ float accL[NCOLS*NN];
  __shared__ float hL[NCOLS*NN];
  __shared__ float gv[256], zv[128], t1v[256];
  __shared__ float colstat[2*NCOLS];
  float* Xs = poolS;

  // ---------------- E0: degrees (block-redundant) ---------------------------
  for (int i = tid; i < NN; i += TPB) accL[i] = 1.0f;            // self loop
  __syncthreads();
  for (int e = tid; e < 800; e += TPB) atomicAdd(&accL[ei[800+e]], 1.0f);
  __syncthreads();
  for (int i = tid; i < NN; i += TPB) dinvS[i] = 1.0f/sqrtf(accL[i]);
  __syncthreads();

  // ---------------- E1: GEMM1 x@W1 (own cols) + GCN1 -> hT ------------------
  for (int u = tid; u < NCOLS*NN; u += TPB){
    int cl = u/NN, i = u - cl*NN, c = p + PBLK*cl;
    if (c < 256){
      float s = 0.f;
      for (int k = 0; k < 64; k++) s += x[i*64+k]*W1[k*256+c];
      hL[u] = s;
    }
  }
  __syncthreads();
  gcn_bn_relu(hL, b1, g1, bt1, ei, dinvS, accL, colstat, p, tid);
  for (int u2 = tid; u2 < 40*NCOLS; u2 += TPB){       // export own rows of hT
    int cl = u2/40, i2 = (u2 - cl*40)*2, c = p + PBLK*cl;
    if (c < 256) st_f2g(&hT[c*NN+i2], accL[cl*NN+i2], accL[cl*NN+i2+1]);
  }
  __syncthreads();                                     // drains export stores
  if (tid == 0) st_i32g(&eflag[p*32], 1);

  // ---------------- E2: GEMM2 h@W2 via 4 chunked LDS tiles ------------------
  if (tid < PBLK){
    while (ld_i32g(&eflag[tid*32]) < 1) __builtin_amdgcn_s_sleep(1);
  }
  __syncthreads();                                     // gate ALL waves
  {
    const int cl = tid/20, iq = tid - 20*cl, c = p + PBLK*cl;
    const int i0 = 4*iq;
    const bool valid = (tid < 20*NCOLS) && (c < 256);
    float a0=0.f, a1=0.f, a2=0.f, a3=0.f;
    for (int ch = 0; ch < 4; ch++){
      const int k0 = 64*ch;
      __syncthreads();                                 // chunk buffer free
      #pragma unroll
      for (int r = 0; r < 8; r++){                     // 5120 floats coalesced
        int u = tid + TPB*r;
        float2 hv = ld_f2g(&hT[k0*NN + 2*u]);
        poolS[2*u] = hv.x; poolS[2*u+1] = hv.y;
      }
      __syncthreads();
      if (valid){
        for (int kk = 0; kk < 64; kk++){
          float wv = W2[(k0+kk)*256 + c];
          float4 hv = *(const float4*)&poolS[kk*NN + i0];
          a0 += hv.x*wv; a1 += hv.y*wv; a2 += hv.z*wv; a3 += hv.w*wv;
        }
      }
    }
    __syncthreads();
    if (valid){
      hL[cl*NN+i0+0]=a0; hL[cl*NN+i0+1]=a1; hL[cl*NN+i0+2]=a2; hL[cl*NN+i0+3]=a3;
    }
  }
  __syncthreads();
  gcn_bn_relu(hL, b2, g2, bt2, ei, dinvS, accL, colstat, p, tid);
  if (tid < 16*NCOLS){                                 // pool own cols -> gvS
    int g = tid >> 4, s = tid & 15, c = p + PBLK*g;
    if (c < 256){
      float sm = 0.f;
      #pragma unroll
      for (int i = 0; i < 5; i++) sm += accL[g*NN + s + 16*i];
      #pragma unroll
      for (int k = 1; k < 16; k <<= 1) sm += __shfl_xor(sm, k, 64);
      if (s == 0) st_f32g(&gvS[c], sm*(1.0f/NN));
    }
  }
  __syncthreads();                                     // drains gvS stores
  if (tid == 0) st_i32g(&eflag[p*32], 2);

  // ---------------- E3: z, t1 (block-redundant; weights are inputs) ---------
  if (tid < PBLK){
    while (ld_i32g(&eflag[tid*32]) < 2) __builtin_amdgcn_s_sleep(1);
  }
  __syncthreads();
  if (tid < 256) gv[tid] = ld_f32g(&gvS[tid]);
  __syncthreads();
  if (tid < 128){
    int c = tid;
    float smu = bmu[c], slv = blv[c];
    for (int k = 0; k < 256; k++){
      float g = gv[k];
      smu += g*Wmu[k*128+c];
      slv += g*Wlv[k*128+c];
    }
    slv = fminf(fmaxf(slv, -4.f), 4.f);
    zv[c] = smu + eps[c]*expf(0.5f*slv);
  }
  __syncthreads();
  if (tid < 256){
    float s = be1[tid];
    for (int k = 0; k < 128; k++) s += zv[k]*We1[k*256+tid];
    t1v[tid] = fmaxf(s, 0.f);
  }
  __syncthreads();

  // ---------------- E4: OWN B rows 4p..4p+3 -> BmL (LDS only) ---------------
  if (tid < 316){
    int r = tid/79, jj = tid - 79*r;
    int a = 4*p + r;
    int j = jj + (jj >= a ? 1 : 0);
    int lo = a < j ? a : j, hi = a < j ? j : a;
    int off = lo*(159-lo)/2 + (hi-lo-1);               // triu(k=1) flat index
    float s = be2[off];
    for (int k = 0; k < 256; k++) s += t1v[k]*We2[k*3160+off];
    BmL[r*RPB + j] = 1.0f/(1.0f + expf(-s));
  } else {
    int r = tid-316;
    BmL[r*RPB + 4*p + r] = 1.0f;                       // diag = 1
  }
  __syncthreads();

  // ---------------- E5: per-lane register caches ----------------------------
  const int w  = tid >> 6;
  const int l  = tid & 63;
  const int il = 16*w + (l & 15);    // row i (== j in M phase)
  const int ae = l >> 4;             // local column 0..3
  const int al = 4*p + ae;           // global column a

  float4 Af[20];
  float degA = 0.f;
  #pragma unroll
  for (int c = 0; c < 20; c++){
    int j0 = 4*c;
    int4 ar = *(const int4*)&adj[il*NN+j0];
    int q0 = adj[(j0+0)*NN+il];
    int q1 = adj[(j0+1)*NN+il];
    int q2 = adj[(j0+2)*NN+il];
    int q3 = adj[(j0+3)*NN+il];
    float4 a;
    a.x = ((ar.x|q0) != 0 || il == j0+0) ? 1.f : 0.f;
    a.y = ((ar.y|q1) != 0 || il == j0+1) ? 1.f : 0.f;
    a.z = ((ar.z|q2) != 0 || il == j0+2) ? 1.f : 0.f;
    a.w = ((ar.w|q3) != 0 || il == j0+3) ? 1.f : 0.f;
    Af[c] = a;
    degA += (a.x+a.y)+(a.z+a.w);
  }

  float4 Bf[20];
  float degB = 0.f;
  #pragma unroll
  for (int c = 0; c < 20; c++){
    float4 b = *(const float4*)&BmL[ae*RPB + 4*c];
    Bf[c] = b;
    degB += (b.x+b.y)+(b.z+b.w);
  }
  const float ns = 1.0f/(fabsf(degA-degB)+1.0f);
  {                                   // b==a exclusion (valid since X,B >= 0)
    if      (ae == 0) Bf[p].x = 0.f;
    else if (ae == 1) Bf[p].y = 0.f;
    else if (ae == 2) Bf[p].z = 0.f;
    else              Bf[p].w = 0.f;
  }
  __syncthreads();                    // BmL reads done; poolS reuse below

  // ---------------- MPM: 50 iterations, data-as-flag sync -------------------
  for (int u = tid; u < NN*RP; u += TPB) Xs[u] = 1.0f/NN;   // X0, ||X0||=1
  __syncthreads();
  float xn = 0.f;
  float sc = 1.0f;
  for (int t = 0; t < 50; t++){
    if (t > 0){
      // stage U(t-1): poll the DATA (all values strictly > 0 when written;
      // buffer was zeroed at launch). Each lane re-polls only its own
      // pending chunks -> no shared-line contention, no flag hop.
      const float* Xsrc = Xbase + (t-1)*6400;
      float2 v[10];
      #pragma unroll
      for (int q = 0; q < 10; q++){
        int u = tid + TPB*q, j = u/40, c2 = (u - 40*j)*2;
        v[q] = ld_f2g(&Xsrc[j*NN + c2]);
      }
      bool pending = true;
      while (pending){
        pending = false;
        #pragma unroll
        for (int q = 0; q < 10; q++){
          if (v[q].x == 0.f || v[q].y == 0.f){
            int u = tid + TPB*q, j = u/40, c2 = (u - 40*j)*2;
            v[q] = ld_f2g(&Xsrc[j*NN + c2]);
            pending = true;
          }
        }
      }
      float sq = 0.f;
      #pragma unroll
      for (int q = 0; q < 10; q++){
        int u = tid + TPB*q, j = u/40, c2 = (u - 40*j)*2;
        Xs[j*RP + c2]     = v[q].x;
        Xs[j*RP + c2 + 1] = v[q].y;
        sq += v[q].x*v[q].x + v[q].y*v[q].y;
      }
      sq = wave_sum(sq);
      if (l == 0) red[w] = sq;
      __syncthreads();                // Xs staged + red ready (all waves)
      sc = 1.0f/sqrtf(((red[0]+red[1])+(red[2]+red[3]))+red[4]);
    }

    // M[il][al] = max_{b != al} X[il][b]*B[al][b]
    float m = 0.f;
    #pragma unroll
    for (int c = 0; c < 20; c++){
      float4 xv = *(const float4*)&Xs[il*RP+4*c];
      float p0 = xv.x*Bf[c].x, p1 = xv.y*Bf[c].y, p2 = xv.z*Bf[c].z, p3 = xv.w*Bf[c].w;
      m = fmaxf(m, fmaxf(fmaxf(p0,p1), fmaxf(p2,p3)));
    }
    float xnode = Xs[il*RP+al];
    MtL[ae*RP+il] = m;
    __syncthreads();

    // edge[il][al] = sum_j A[il][j]*M[j][al] - M[il][al]   (A[i][i]=1)
    float e0=0.f,e1=0.f,e2=0.f,e3=0.f;
    #pragma unroll
    for (int c = 0; c < 20; c++){
      float4 mv = *(const float4*)&MtL[ae*RP+4*c];
      e0 += Af[c].x*mv.x; e1 += Af[c].y*mv.y; e2 += Af[c].z*mv.z; e3 += Af[c].w*mv.w;
    }
    float edge = ((e0+e1)+(e2+e3)) - m;
    xn = sc*(ns*xnode + edge);        // xn > 0 always (data-as-flag validity)

    // publish own slab of U(t) to the fresh per-t buffer — no flag needed
    st_f32g(&Xbase[t*6400 + il*NN + al], xn);
  }

  // final normalization: poll U(49), norm computed locally
  {
    const float* Xsrc = Xbase + 49*6400;
    float2 v[10];
    #pragma unroll
    for (int q = 0; q < 10; q++){
      int u = tid + TPB*q, j = u/40, c2 = (u - 40*j)*2;
      v[q] = ld_f2g(&Xsrc[j*NN + c2]);
    }
    bool pending = true;
    while (pending){
      pending = false;
      #pragma unroll
      for (int q = 0; q < 10; q++){
        if (v[q].x == 0.f || v[q].y == 0.f){
          int u = tid + TPB*q, j = u/40, c2 = (u - 40*j)*2;
          v[q] = ld_f2g(&Xsrc[j*NN + c2]);
          pending = true;
        }
      }
    }
    float sq = 0.f;
    #pragma unroll
    for (int q = 0; q < 10; q++) sq += v[q].x*v[q].x + v[q].y*v[q].y;
    sq = wave_sum(sq);
    if (l == 0) red[w] = sq;
    __syncthreads();
    float scf = 1.0f/sqrtf(((red[0]+red[1])+(red[2]+red[3]))+red[4]);
    out[il*NN+al] = xn * scf;
  }
}

extern "C" void kernel_launch(void* const* d_in, const int* in_sizes, int n_in,
                              void* d_out, int out_size, void* d_ws, size_t ws_size,
                              hipStream_t stream)
{
  (void)in_sizes; (void)n_in; (void)out_size; (void)ws_size;
  // zero the 50 per-iteration U buffers (data-as-flag) + encoder flags:
  // 320000*4 + 20*32*4 = 1,282,560 bytes. ws is re-poisoned each launch.
  hipMemsetAsync(d_ws, 0, 1282560, stream);
  gvae_fused<<<PBLK, TPB, 0, stream>>>(
      (const float*)d_in[0],  (const int*)d_in[1],   (const int*)d_in[2],   (const float*)d_in[3],
      (const float*)d_in[4],  (const float*)d_in[5],  (const float*)d_in[6],  (const float*)d_in[7],
      (const float*)d_in[8],  (const float*)d_in[9],  (const float*)d_in[10], (const float*)d_in[11],
      (const float*)d_in[12], (const float*)d_in[13], (const float*)d_in[14], (const float*)d_in[15],
      (const float*)d_in[16], (const float*)d_in[17], (const float*)d_in[18], (const float*)d_in[19],
      (float*)d_out, (float*)d_ws);
}

// Round 6
// 537.581 us; speedup vs baseline: 1.1385x; 1.0698x over previous
//
#include <hip/hip_runtime.h>

// GraphVAE fused persistent kernel, round 6.
// R1/R3/R4/R5 post-mortem: four different sync schemes all cost ~9.5us/iter.
// R5's FETCH (24MB = exactly one full X refetch per block per iter) shows
// sc1 POLL LOADS bypass L2 and detect fast -> the ~8us residual is on the
// STORE side: relaxed sc1 stores sit DIRTY in the producer XCD's L2 while
// the consumer reads stale data from the coherence point (IF) until the
// line drains. Fix: publish every cross-block word with ATOMIC EXCHANGE
// (device-scope atomics execute AT the coherence point -> immediately
// visible, never dirty-cached). Fire-and-forget; poll loads unchanged.

#define NN 80
#define PBLK 20            // blocks; each owns 4 columns of X
#define TPB 320            // 5 waves
#define RP 84              // Xs row pad (16B-aligned rows, conflict-free)
#define RPB 84             // BmL row pad
#define NCOLS 13           // owned feature columns per block (ceil(256/20))

// ---- sc1 poll loads (bypass L2, read coherence point) ----
__device__ __forceinline__ int ld_i32g(const int* p){
  return __hip_atomic_load((int*)p, __ATOMIC_RELAXED, __HIP_MEMORY_SCOPE_AGENT);
}
__device__ __forceinline__ float2 ld_f2g(const float* p){
  union { unsigned long long u; float2 f; } c;
  c.u = __hip_atomic_load((unsigned long long*)p, __ATOMIC_RELAXED, __HIP_MEMORY_SCOPE_AGENT);
  return c.f;
}
// ---- atomic publish (executes at coherence point, immediately visible) ----
__device__ __forceinline__ void pub_f32(float* p, float v){
  union { unsigned u; float f; } c; c.f = v;
  (void)__hip_atomic_exchange((unsigned*)p, c.u, __ATOMIC_RELAXED, __HIP_MEMORY_SCOPE_AGENT);
}
__device__ __forceinline__ void pub_f2(float* p, float a, float b){
  union { unsigned long long u; float2 f; } c; c.f.x = a; c.f.y = b;
  (void)__hip_atomic_exchange((unsigned long long*)p, c.u, __ATOMIC_RELAXED, __HIP_MEMORY_SCOPE_AGENT);
}
__device__ __forceinline__ void pub_i32(int* p, int v){
  (void)__hip_atomic_exchange(p, v, __ATOMIC_RELAXED, __HIP_MEMORY_SCOPE_AGENT);
}

__device__ __forceinline__ float wave_sum(float v){
  #pragma unroll
  for (int k = 32; k >= 1; k >>= 1) v += __shfl_xor(v, k, 64);
  return v;
}

// GCN aggregate(+self loop)+bias+BatchNorm(train,biased,two-pass var)+ReLU
// for owned columns; result left in accL. inL/accL: LDS [NCOLS][80].
__device__ void gcn_bn_relu(const float* inL, const float* bias, const float* gamma,
                            const float* beta, const int* ei, const float* dinvS,
                            float* accL, float* colstat, int p, int tid)
{
  for (int u = tid; u < NCOLS*NN; u += TPB) accL[u] = 0.f;
  __syncthreads();
  for (int cl = 0; cl < NCOLS; cl++){
    int c = p + PBLK*cl; if (c >= 256) break;
    const float* col = &inL[cl*NN];
    for (int e = tid; e < 800; e += TPB){
      int s = ei[e], d = ei[800+e];
      atomicAdd(&accL[cl*NN + d], col[s]*dinvS[s]*dinvS[d]);
    }
  }
  __syncthreads();
  for (int u = tid; u < NCOLS*NN; u += TPB){
    int cl = u/NN, i = u - cl*NN, c = p + PBLK*cl;
    if (c < 256) accL[u] += inL[u]*dinvS[i]*dinvS[i] + bias[c];
  }
  __syncthreads();
  if (tid < 16*NCOLS){
    int g = tid >> 4, s = tid & 15, c = p + PBLK*g;
    if (c < 256){
      float r[5];
      float sm = 0.f;
      #pragma unroll
      for (int i = 0; i < 5; i++){ r[i] = accL[g*NN + s + 16*i]; sm += r[i]; }
      #pragma unroll
      for (int k = 1; k < 16; k <<= 1) sm += __shfl_xor(sm, k, 64);
      float m = sm*(1.0f/NN);
      float sq = 0.f;
      #pragma unroll
      for (int i = 0; i < 5; i++){ float d = r[i]-m; sq += d*d; }
      #pragma unroll
      for (int k = 1; k < 16; k <<= 1) sq += __shfl_xor(sq, k, 64);
      if (s == 0){
        colstat[2*g]   = m;
        colstat[2*g+1] = 1.0f/sqrtf(sq*(1.0f/NN) + 1e-5f);
      }
    }
  }
  __syncthreads();
  for (int u = tid; u < NCOLS*NN; u += TPB){
    int cl = u/NN, c = p + PBLK*cl;
    if (c < 256){
      float hv = gamma[c]*(accL[u]-colstat[2*cl])*colstat[2*cl+1] + beta[c];
      accL[u] = fmaxf(hv, 0.f);
    }
  }
  __syncthreads();
}

__global__ __launch_bounds__(TPB, 1) void gvae_fused(
    const float* __restrict__ x,  const int* __restrict__ ei, const int* __restrict__ adj,
    const float* __restrict__ eps,
    const float* __restrict__ W1, const float* __restrict__ b1, const float* __restrict__ g1, const float* __restrict__ bt1,
    const float* __restrict__ W2, const float* __restrict__ b2, const float* __restrict__ g2, const float* __restrict__ bt2,
    const float* __restrict__ Wmu,const float* __restrict__ bmu,const float* __restrict__ Wlv,const float* __restrict__ blv,
    const float* __restrict__ We1,const float* __restrict__ be1,const float* __restrict__ We2,const float* __restrict__ be2,
    float* __restrict__ out, float* __restrict__ ws)
{
  const int tid = threadIdx.x;
  const int p   = blockIdx.x;

  // ---- workspace: [Xbase 50*6400 | eflag 20*32 ints | gvS 256 | hT 20480]
  // host memsets Xbase+eflag (1,282,560 B) to zero each launch.
  // gvS/hT need no zeroing (flag-gated, every element atomically published).
  float* Xbase = ws;                   // 50 per-iteration U buffers (data-as-flag)
  int*   eflag = (int*)ws + 320000;    // encoder flags, padded 128B apart
  float* gvS   = ws + 320640;          // pooled g_vec exchange
  float* hT    = ws + 320896;          // layer-1 output, transposed [256][80]

  // poolS: Xs [80][RP] in MPM; hT chunk [64][80] in E2.
  __shared__ float poolS[NN*RP];
  __shared__ float MtL[4*RP];
  __shared__ float BmL[4*RPB];         // B rows 4p..4p+3 (local only)
  __shared__ float red[8];
  __shared__ float dinvS[NN];
  __shared__ float accL[NCOLS*NN];
  __shared__ float hL[NCOLS*NN];
  __shared__ float gv[256], zv[128], t1v[256];
  __shared__ float colstat[2*NCOLS];
  float* Xs = poolS;

  // ---------------- E0: degrees (block-redundant) ---------------------------
  for (int i = tid; i < NN; i += TPB) accL[i] = 1.0f;            // self loop
  __syncthreads();
  for (int e = tid; e < 800; e += TPB) atomicAdd(&accL[ei[800+e]], 1.0f);
  __syncthreads();
  for (int i = tid; i < NN; i += TPB) dinvS[i] = 1.0f/sqrtf(accL[i]);
  __syncthreads();

  // ---------------- E1: GEMM1 x@W1 (own cols) + GCN1 -> hT ------------------
  for (int u = tid; u < NCOLS*NN; u += TPB){
    int cl = u/NN, i = u - cl*NN, c = p + PBLK*cl;
    if (c < 256){
      float s = 0.f;
      for (int k = 0; k < 64; k++) s += x[i*64+k]*W1[k*256+c];
      hL[u] = s;
    }
  }
  __syncthreads();
  gcn_bn_relu(hL, b1, g1, bt1, ei, dinvS, accL, colstat, p, tid);
  for (int u2 = tid; u2 < 40*NCOLS; u2 += TPB){       // export own rows of hT
    int cl = u2/40, i2 = (u2 - cl*40)*2, c = p + PBLK*cl;
    if (c < 256) pub_f2(&hT[c*NN+i2], accL[cl*NN+i2], accL[cl*NN+i2+1]);
  }
  __syncthreads();                                     // drains export atomics
  if (tid == 0) pub_i32(&eflag[p*32], 1);

  // ---------------- E2: GEMM2 h@W2 via 4 chunked LDS tiles ------------------
  if (tid < PBLK){
    while (ld_i32g(&eflag[tid*32]) < 1) __builtin_amdgcn_s_sleep(1);
  }
  __syncthreads();                                     // gate ALL waves
  {
    const int cl = tid/20, iq = tid - 20*cl, c = p + PBLK*cl;
    const int i0 = 4*iq;
    const bool valid = (tid < 20*NCOLS) && (c < 256);
    float a0=0.f, a1=0.f, a2=0.f, a3=0.f;
    for (int ch = 0; ch < 4; ch++){
      const int k0 = 64*ch;
      __syncthreads();                                 // chunk buffer free
      #pragma unroll
      for (int r = 0; r < 8; r++){                     // 5120 floats coalesced
        int u = tid + TPB*r;
        float2 hv = ld_f2g(&hT[k0*NN + 2*u]);
        poolS[2*u] = hv.x; poolS[2*u+1] = hv.y;
      }
      __syncthreads();
      if (valid){
        for (int kk = 0; kk < 64; kk++){
          float wv = W2[(k0+kk)*256 + c];
          float4 hv = *(const float4*)&poolS[kk*NN + i0];
          a0 += hv.x*wv; a1 += hv.y*wv; a2 += hv.z*wv; a3 += hv.w*wv;
        }
      }
    }
    __syncthreads();
    if (valid){
      hL[cl*NN+i0+0]=a0; hL[cl*NN+i0+1]=a1; hL[cl*NN+i0+2]=a2; hL[cl*NN+i0+3]=a3;
    }
  }
  __syncthreads();
  gcn_bn_relu(hL, b2, g2, bt2, ei, dinvS, accL, colstat, p, tid);
  if (tid < 16*NCOLS){                                 // pool own cols -> gvS
    int g = tid >> 4, s = tid & 15, c = p + PBLK*g;
    if (c < 256){
      float sm = 0.f;
      #pragma unroll
      for (int i = 0; i < 5; i++) sm += accL[g*NN + s + 16*i];
      #pragma unroll
      for (int k = 1; k < 16; k <<= 1) sm += __shfl_xor(sm, k, 64);
      if (s == 0) pub_f32(&gvS[c], sm*(1.0f/NN));
    }
  }
  __syncthreads();                                     // drains gvS atomics
  if (tid == 0) pub_i32(&eflag[p*32], 2);

  // ---------------- E3: z, t1 (block-redundant; weights are inputs) ---------
  if (tid < PBLK){
    while (ld_i32g(&eflag[tid*32]) < 2) __builtin_amdgcn_s_sleep(1);
  }
  __syncthreads();
  if (tid < 256){
    float2 gvv = ld_f2g(&gvS[2*(tid & 127)]);
    if (tid < 128){ gv[2*tid] = gvv.x; gv[2*tid+1] = gvv.y; }
  }
  __syncthreads();
  if (tid < 128){
    int c = tid;
    float smu = bmu[c], slv = blv[c];
    for (int k = 0; k < 256; k++){
      float g = gv[k];
      smu += g*Wmu[k*128+c];
      slv += g*Wlv[k*128+c];
    }
    slv = fminf(fmaxf(slv, -4.f), 4.f);
    zv[c] = smu + eps[c]*expf(0.5f*slv);
  }
  __syncthreads();
  if (tid < 256){
    float s = be1[tid];
    for (int k = 0; k < 128; k++) s += zv[k]*We1[k*256+tid];
    t1v[tid] = fmaxf(s, 0.f);
  }
  __syncthreads();

  // ---------------- E4: OWN B rows 4p..4p+3 -> BmL (LDS only) ---------------
  if (tid < 316){
    int r = tid/79, jj = tid - 79*r;
    int a = 4*p + r;
    int j = jj + (jj >= a ? 1 : 0);
    int lo = a < j ? a : j, hi = a < j ? j : a;
    int off = lo*(159-lo)/2 + (hi-lo-1);               // triu(k=1) flat index
    float s = be2[off];
    for (int k = 0; k < 256; k++) s += t1v[k]*We2[k*3160+off];
    BmL[r*RPB + j] = 1.0f/(1.0f + expf(-s));
  } else {
    int r = tid-316;
    BmL[r*RPB + 4*p + r] = 1.0f;                       // diag = 1
  }
  __syncthreads();

  // ---------------- E5: per-lane register caches ----------------------------
  const int w  = tid >> 6;
  const int l  = tid & 63;
  const int il = 16*w + (l & 15);    // row i (== j in M phase)
  const int ae = l >> 4;             // local column 0..3
  const int al = 4*p + ae;           // global column a

  float4 Af[20];
  float degA = 0.f;
  #pragma unroll
  for (int c = 0; c < 20; c++){
    int j0 = 4*c;
    int4 ar = *(const int4*)&adj[il*NN+j0];
    int q0 = adj[(j0+0)*NN+il];
    int q1 = adj[(j0+1)*NN+il];
    int q2 = adj[(j0+2)*NN+il];
    int q3 = adj[(j0+3)*NN+il];
    float4 a;
    a.x = ((ar.x|q0) != 0 || il == j0+0) ? 1.f : 0.f;
    a.y = ((ar.y|q1) != 0 || il == j0+1) ? 1.f : 0.f;
    a.z = ((ar.z|q2) != 0 || il == j0+2) ? 1.f : 0.f;
    a.w = ((ar.w|q3) != 0 || il == j0+3) ? 1.f : 0.f;
    Af[c] = a;
    degA += (a.x+a.y)+(a.z+a.w);
  }

  float4 Bf[20];
  float degB = 0.f;
  #pragma unroll
  for (int c = 0; c < 20; c++){
    float4 b = *(const float4*)&BmL[ae*RPB + 4*c];
    Bf[c] = b;
    degB += (b.x+b.y)+(b.z+b.w);
  }
  const float ns = 1.0f/(fabsf(degA-degB)+1.0f);
  {                                   // b==a exclusion (valid since X,B >= 0)
    if      (ae == 0) Bf[p].x = 0.f;
    else if (ae == 1) Bf[p].y = 0.f;
    else if (ae == 2) Bf[p].z = 0.f;
    else              Bf[p].w = 0.f;
  }
  __syncthreads();                    // BmL reads done; poolS reuse below

  // ---------------- MPM: 50 iterations, data-as-flag sync -------------------
  for (int u = tid; u < NN*RP; u += TPB) Xs[u] = 1.0f/NN;   // X0, ||X0||=1
  __syncthreads();
  float xn = 0.f;
  float sc = 1.0f;
  for (int t = 0; t < 50; t++){
    if (t > 0){
      // stage U(t-1): poll the DATA (all values strictly > 0 when written;
      // buffer zeroed at launch; producers publish via coherence-point
      // atomics so values are visible as soon as they exist).
      const float* Xsrc = Xbase + (t-1)*6400;
      float2 v[10];
      #pragma unroll
      for (int q = 0; q < 10; q++){
        int u = tid + TPB*q, j = u/40, c2 = (u - 40*j)*2;
        v[q] = ld_f2g(&Xsrc[j*NN + c2]);
      }
      bool pending = true;
      while (pending){
        pending = false;
        #pragma unroll
        for (int q = 0; q < 10; q++){
          if (v[q].x == 0.f || v[q].y == 0.f){
            int u = tid + TPB*q, j = u/40, c2 = (u - 40*j)*2;
            v[q] = ld_f2g(&Xsrc[j*NN + c2]);
            pending = true;
          }
        }
      }
      float sq = 0.f;
      #pragma unroll
      for (int q = 0; q < 10; q++){
        int u = tid + TPB*q, j = u/40, c2 = (u - 40*j)*2;
        Xs[j*RP + c2]     = v[q].x;
        Xs[j*RP + c2 + 1] = v[q].y;
        sq += v[q].x*v[q].x + v[q].y*v[q].y;
      }
      sq = wave_sum(sq);
      if (l == 0) red[w] = sq;
      __syncthreads();                // Xs staged + red ready (all waves)
      sc = 1.0f/sqrtf(((red[0]+red[1])+(red[2]+red[3]))+red[4]);
    }

    // M[il][al] = max_{b != al} X[il][b]*B[al][b]
    float m = 0.f;
    #pragma unroll
    for (int c = 0; c < 20; c++){
      float4 xv = *(const float4*)&Xs[il*RP+4*c];
      float p0 = xv.x*Bf[c].x, p1 = xv.y*Bf[c].y, p2 = xv.z*Bf[c].z, p3 = xv.w*Bf[c].w;
      m = fmaxf(m, fmaxf(fmaxf(p0,p1), fmaxf(p2,p3)));
    }
    float xnode = Xs[il*RP+al];
    MtL[ae*RP+il] = m;
    __syncthreads();

    // edge[il][al] = sum_j A[il][j]*M[j][al] - M[il][al]   (A[i][i]=1)
    float e0=0.f,e1=0.f,e2=0.f,e3=0.f;
    #pragma unroll
    for (int c = 0; c < 20; c++){
      float4 mv = *(const float4*)&MtL[ae*RP+4*c];
      e0 += Af[c].x*mv.x; e1 += Af[c].y*mv.y; e2 += Af[c].z*mv.z; e3 += Af[c].w*mv.w;
    }
    float edge = ((e0+e1)+(e2+e3)) - m;
    xn = sc*(ns*xnode + edge);        // xn > 0 always (data-as-flag validity)

    // publish own element of U(t) via coherence-point atomic (fire & forget)
    pub_f32(&Xbase[t*6400 + il*NN + al], xn);
  }

  // final normalization: poll U(49), norm computed locally
  {
    const float* Xsrc = Xbase + 49*6400;
    float2 v[10];
    #pragma unroll
    for (int q = 0; q < 10; q++){
      int u = tid + TPB*q, j = u/40, c2 = (u - 40*j)*2;
      v[q] = ld_f2g(&Xsrc[j*NN + c2]);
    }
    bool pending = true;
    while (pending){
      pending = false;
      #pragma unroll
      for (int q = 0; q < 10; q++){
        if (v[q].x == 0.f || v[q].y == 0.f){
          int u = tid + TPB*q, j = u/40, c2 = (u - 40*j)*2;
          v[q] = ld_f2g(&Xsrc[j*NN + c2]);
          pending = true;
        }
      }
    }
    float sq = 0.f;
    #pragma unroll
    for (int q = 0; q < 10; q++) sq += v[q].x*v[q].x + v[q].y*v[q].y;
    sq = wave_sum(sq);
    if (l == 0) red[w] = sq;
    __syncthreads();
    float scf = 1.0f/sqrtf(((red[0]+red[1])+(red[2]+red[3]))+red[4]);
    out[il*NN+al] = xn * scf;
  }
}

extern "C" void kernel_launch(void* const* d_in, const int* in_sizes, int n_in,
                              void* d_out, int out_size, void* d_ws, size_t ws_size,
                              hipStream_t stream)
{
  (void)in_sizes; (void)n_in; (void)out_size; (void)ws_size;
  // zero the 50 per-iteration U buffers (data-as-flag) + encoder flags:
  // 320000*4 + 20*32*4 = 1,282,560 bytes. ws is re-poisoned each launch.
  hipMemsetAsync(d_ws, 0, 1282560, stream);
  gvae_fused<<<PBLK, TPB, 0, stream>>>(
      (const float*)d_in[0],  (const int*)d_in[1],   (const int*)d_in[2],   (const float*)d_in[3],
      (const float*)d_in[4],  (const float*)d_in[5],  (const float*)d_in[6],  (const float*)d_in[7],
      (const float*)d_in[8],  (const float*)d_in[9],  (const float*)d_in[10], (const float*)d_in[11],
      (const float*)d_in[12], (const float*)d_in[13], (const float*)d_in[14], (const float*)d_in[15],
      (const float*)d_in[16], (const float*)d_in[17], (const float*)d_in[18], (const float*)d_in[19],
      (float*)d_out, (float*)d_ws);
}